// Round 13
// baseline (361.166 us; speedup 1.0000x reference)
//
#include <hip/hip_runtime.h>
#include <hip/hip_cooperative_groups.h>
#include <cstdint>
#include <cstddef>

namespace cg = cooperative_groups;

typedef __bf16 bf16;
typedef __bf16 bf16x4 __attribute__((ext_vector_type(4)));
typedef __bf16 bf16x8 __attribute__((ext_vector_type(8)));
typedef float  f32x4  __attribute__((ext_vector_type(4)));

#define BATCH 4
#define SEQ   2048
#define DIM   1024
#define LDP   2112   // padded leading dim for P and Vt

// RNE float -> bf16
__device__ __forceinline__ bf16 to_bf16(float f) {
    unsigned u = __builtin_bit_cast(unsigned, f);
    u += 0x7fffu + ((u >> 16) & 1u);
    unsigned short h = (unsigned short)(u >> 16);
    return __builtin_bit_cast(bf16, h);
}

// async global->LDS, 16B per lane. LDS base must be wave-uniform; HW adds lane*16.
__device__ __forceinline__ void load16_lds(const bf16* g, bf16* l) {
    __builtin_amdgcn_global_load_lds(
        (__attribute__((address_space(1))) void*)(g),
        (__attribute__((address_space(3))) void*)(l),
        16, 0, 0);
}

#define BARRIER() __builtin_amdgcn_s_barrier()
#define LGKM0()   asm volatile("s_waitcnt lgkmcnt(0)")
#define VM0()     asm volatile("s_waitcnt vmcnt(0)")
#define VM3()     asm volatile("s_waitcnt vmcnt(3)")
#define VM4()     asm volatile("s_waitcnt vmcnt(4)")

// ---------------------------------------------------------------------------
// r13: FUSED cooperative kernel. r12 analysis: dispatch-sum (~140 us of
// measured/model kernel time) << 226 us wall -> tens of us of inter-launch
// overhead across 5 sequential dispatches. All four GEMM phases use EXACTLY
// 256 blocks -> perfect co-resident cooperative grid (1 block/CU, 101 KB
// LDS). Phase bodies = r12's proven kernels verbatim (p3w: 256x256 BK=32
// 3-slot counted-vmcnt; p3s: 256x128 variant); grid.sync() replaces kernel
// boundaries (provides the cross-XCD fencing). prep = 512-thread grid-stride
// phase. Epilogue buffers alias nothing (separate 5 KB; 101 KB total LDS).
// ---------------------------------------------------------------------------

// stage 128 rows x 32 k (8 KB): 1 gload_lds / thread (512 threads).
__device__ __forceinline__ void stage_r32(
    const bf16* __restrict__ srcRow0, int ld, int k0, bf16* dstBase)
{
    const int t = threadIdx.x;                  // 0..511
    const int r = t >> 2;                       // row 0..127
    const int c = (t & 3) ^ ((r >> 1) & 3);     // pre-swizzled global chunk
    load16_lds(srcRow0 + (size_t)r * ld + k0 + c * 8,
               dstBase + (t >> 6) * 512);       // wave-uniform LDS base
}

// ---- p3w: 256x256, BK=32, 8 waves 2Mx4N, per-wave 128x64, acc[8][4] ----
__device__ __forceinline__ void gemm_p3w_core(
    const bf16* __restrict__ Ablk, const bf16* __restrict__ Bblk,
    int K, int lda, int ldb, bf16* As, bf16* Bs, f32x4 acc[8][4])
{
    const int tid  = threadIdx.x;
    const int lane = tid & 63;
    const int wave = tid >> 6;
    const int wr   = wave >> 2;
    const int wc   = wave & 3;
    const int r16  = lane & 15;
    const int g    = lane >> 4;
    const int NT   = K >> 5;
    const int arow0 = wr * 128 + r16;
    const int brow0 = wc * 64 + r16;

    stage_r32(Ablk, lda, 0, As);
    stage_r32(Ablk + (size_t)128 * lda, lda, 0, As + 4096);
    stage_r32(Bblk, ldb, 0, Bs);
    stage_r32(Bblk + (size_t)128 * ldb, ldb, 0, Bs + 4096);
    stage_r32(Ablk, lda, 32, As + 8192);
    stage_r32(Ablk + (size_t)128 * lda, lda, 32, As + 8192 + 4096);
    stage_r32(Bblk, ldb, 32, Bs + 8192);
    stage_r32(Bblk + (size_t)128 * ldb, ldb, 32, Bs + 8192 + 4096);
    VM4();
    BARRIER();

    int c0 = 0, c2 = 2;
    for (int t = 0; t < NT; ++t) {
        bf16* Ac = As + c0 * 8192;
        bf16* Bc = Bs + c0 * 8192;

        bf16x8 a[8], b[4];
#pragma unroll
        for (int n = 0; n < 4; ++n) {
            const int R = brow0 + n * 16;
            b[n] = *(const bf16x8*)(Bc + R * 32 + ((g ^ ((R >> 1) & 3)) * 8));
        }
#pragma unroll
        for (int m = 0; m < 8; ++m) {
            const int R = arow0 + m * 16;
            a[m] = *(const bf16x8*)(Ac + R * 32 + ((g ^ ((R >> 1) & 3)) * 8));
        }
        if (t + 2 < NT) {
            const int k2 = (t + 2) << 5;
            bf16* An = As + c2 * 8192;
            bf16* Bn = Bs + c2 * 8192;
            stage_r32(Ablk, lda, k2, An);
            stage_r32(Ablk + (size_t)128 * lda, lda, k2, An + 4096);
            stage_r32(Bblk, ldb, k2, Bn);
            stage_r32(Bblk + (size_t)128 * ldb, ldb, k2, Bn + 4096);
        }
        __builtin_amdgcn_s_setprio(1);
#pragma unroll
        for (int m = 0; m < 8; ++m)
#pragma unroll
            for (int n = 0; n < 4; ++n)
                acc[m][n] = __builtin_amdgcn_mfma_f32_16x16x32_bf16(
                    a[m], b[n], acc[m][n], 0, 0, 0);
        __builtin_amdgcn_s_setprio(0);

        LGKM0();
        if (t + 1 < NT) {
            if (t + 2 < NT) { VM4(); } else { VM0(); }
        }
        BARRIER();
        c0 = (c0 == 2) ? 0 : c0 + 1;
        c2 = (c2 == 2) ? 0 : c2 + 1;
    }
}

// ---- p3s: 256x128, BK=32, 8 waves 4Mx2N, per-wave 64x64, acc[4][4] -----
__device__ __forceinline__ void gemm_p3s_core(
    const bf16* __restrict__ Ablk, const bf16* __restrict__ Bblk,
    int K, int lda, int ldb, bf16* As, bf16* Bs, f32x4 acc[4][4])
{
    const int tid  = threadIdx.x;
    const int lane = tid & 63;
    const int wave = tid >> 6;
    const int wr   = wave >> 1;
    const int wc   = wave & 1;
    const int r16  = lane & 15;
    const int g    = lane >> 4;
    const int NT   = K >> 5;
    const int arow0 = wr * 64 + r16;
    const int brow0 = wc * 64 + r16;

    stage_r32(Ablk, lda, 0, As);
    stage_r32(Ablk + (size_t)128 * lda, lda, 0, As + 4096);
    stage_r32(Bblk, ldb, 0, Bs);
    stage_r32(Ablk, lda, 32, As + 8192);
    stage_r32(Ablk + (size_t)128 * lda, lda, 32, As + 8192 + 4096);
    stage_r32(Bblk, ldb, 32, Bs + 4096);
    VM3();
    BARRIER();

    int c0 = 0, c2 = 2;
    for (int t = 0; t < NT; ++t) {
        bf16* Ac = As + c0 * 8192;
        bf16* Bc = Bs + c0 * 4096;

        bf16x8 a[4], b[4];
#pragma unroll
        for (int n = 0; n < 4; ++n) {
            const int R = brow0 + n * 16;
            b[n] = *(const bf16x8*)(Bc + R * 32 + ((g ^ ((R >> 1) & 3)) * 8));
        }
#pragma unroll
        for (int m = 0; m < 4; ++m) {
            const int R = arow0 + m * 16;
            a[m] = *(const bf16x8*)(Ac + R * 32 + ((g ^ ((R >> 1) & 3)) * 8));
        }
        if (t + 2 < NT) {
            const int k2 = (t + 2) << 5;
            bf16* An = As + c2 * 8192;
            bf16* Bn = Bs + c2 * 4096;
            stage_r32(Ablk, lda, k2, An);
            stage_r32(Ablk + (size_t)128 * lda, lda, k2, An + 4096);
            stage_r32(Bblk, ldb, k2, Bn);
        }
        __builtin_amdgcn_s_setprio(1);
#pragma unroll
        for (int m = 0; m < 4; ++m)
#pragma unroll
            for (int n = 0; n < 4; ++n)
                acc[m][n] = __builtin_amdgcn_mfma_f32_16x16x32_bf16(
                    a[m], b[n], acc[m][n], 0, 0, 0);
        __builtin_amdgcn_s_setprio(0);

        LGKM0();
        if (t + 1 < NT) {
            if (t + 2 < NT) { VM3(); } else { VM0(); }
        }
        BARRIER();
        c0 = (c0 == 2) ? 0 : c0 + 1;
        c2 = (c2 == 2) ? 0 : c2 + 1;
    }
}

// bf16 C-writer (256x256 core, per-wave 128x64)
__device__ __forceinline__ void write_c256w(
    bf16* __restrict__ Cb, int ldc, const f32x4 acc[8][4])
{
    const int lane = threadIdx.x & 63;
    const int wave = threadIdx.x >> 6;
    const int wr = wave >> 2, wc = wave & 3;
    const int r16 = lane & 15, g = lane >> 4;
    const int row0 = wr * 128 + g * 4;
    const int col0 = wc * 64 + r16;
#pragma unroll
    for (int m = 0; m < 8; ++m)
#pragma unroll
        for (int n = 0; n < 4; ++n)
#pragma unroll
            for (int rr = 0; rr < 4; ++rr)
                Cb[(size_t)(row0 + m * 16 + rr) * ldc + col0 + n * 16] =
                    to_bf16(acc[m][n][rr]);
}

// bf16 C-writer (256x128 core, per-wave 64x64)
__device__ __forceinline__ void write_c128s(
    bf16* __restrict__ Cb, int ldc, const f32x4 acc[4][4])
{
    const int lane = threadIdx.x & 63;
    const int wave = threadIdx.x >> 6;
    const int wr = wave >> 1, wc = wave & 1;
    const int r16 = lane & 15, g = lane >> 4;
    const int row0 = wr * 64 + g * 4;
    const int col0 = wc * 64 + r16;
#pragma unroll
    for (int m = 0; m < 4; ++m)
#pragma unroll
        for (int n = 0; n < 4; ++n)
#pragma unroll
            for (int rr = 0; rr < 4; ++rr)
                Cb[(size_t)(row0 + m * 16 + rr) * ldc + col0 + n * 16] =
                    to_bf16(acc[m][n][rr]);
}

// ---------------------------------------------------------------------------
// The fused kernel: 256 blocks x 512 threads, cooperative.
// ---------------------------------------------------------------------------
__global__ __launch_bounds__(512, 2) void fused_attn(
    const float* __restrict__ x,  const float* __restrict__ wq,
    const float* __restrict__ wk, const float* __restrict__ wv,
    bf16* __restrict__ xb, bf16* __restrict__ Wt,
    bf16* __restrict__ Q,  bf16* __restrict__ Kb, bf16* __restrict__ Vt,
    bf16* __restrict__ P,  float* __restrict__ lsumP,
    float* __restrict__ out)
{
    cg::grid_group grid = cg::this_grid();
    __shared__ bf16 As[24576];      // 48 KB
    __shared__ bf16 Bs[24576];      // 48 KB
    __shared__ float rbuf[256][4];  // scores epilogue partials (4 KB)
    __shared__ float sbuf[256];     // pv row sums (1 KB)

    const int p   = blockIdx.x;     // 0..255
    const int tid = threadIdx.x;
    const int xq  = p & 7, s = p >> 3;

    // ================= phase 0: prep (grid-stride) =================
    {
        const float4* x4 = (const float4*)x;
#pragma unroll 4
        for (int i = 0; i < 16; ++i) {
            const size_t idx = (size_t)i * 131072 + (size_t)p * 512 + tid;
            const float4 v = x4[idx];
            bf16x4 o = { to_bf16(v.x), to_bf16(v.y), to_bf16(v.z), to_bf16(v.w) };
            *(bf16x4*)(xb + idx * 4) = o;
        }
        float (*tb)[32][33] = (float(*)[32][33])As;
        const int ts = tid >> 8;          // 0/1: tile this half handles
        const int tl = tid & 255;
        const int tx = tl & 31, ty = tl >> 5;   // ty 0..7
        for (int ii = 0; ii < 6; ++ii) {
            const int tile = p * 12 + ii * 2 + ts;
            const int sel = tile >> 10, rem = tile & 1023;
            const int n0 = (rem & 31) * 32, k0 = (rem >> 5) * 32;
            const float* w = (sel == 0) ? wq : (sel == 1) ? wk : wv;
#pragma unroll
            for (int j = 0; j < 32; j += 8)
                tb[ts][ty + j][tx] = w[(size_t)(k0 + ty + j) * 1024 + n0 + tx];
            __syncthreads();
            bf16* dst = Wt + (size_t)sel * 1024 * 1024;
#pragma unroll
            for (int j = 0; j < 32; j += 8)
                dst[(size_t)(n0 + ty + j) * 1024 + k0 + tx] =
                    to_bf16(tb[ts][tx][ty + j]);
            __syncthreads();
        }
    }
    grid.sync();

    // ================= phase 1: proj_qk (p3w) =================
    {
        f32x4 acc[8][4] = {};
        const int my = xq * 4 + (s >> 3);         // 0..31
        const int j  = s & 7;                     // 0..7
        const bf16* Ab = xb + (size_t)my * 256 * DIM;
        const bf16* Bb = Wt + (size_t)((j >> 2) ? DIM * DIM : 0)
                            + (size_t)(j & 3) * 256 * DIM;
        bf16* dst = (j >> 2) ? Kb : Q;
        bf16* Cb = dst + (size_t)my * 256 * DIM + (size_t)(j & 3) * 256;
        gemm_p3w_core(Ab, Bb, DIM, DIM, DIM, As, Bs, acc);
        write_c256w(Cb, DIM, acc);
    }
    grid.sync();

    // ================= phase 2: proj_v (p3s) =================
    {
        f32x4 acc[4][4] = {};
        const int bz = xq & 3;
        const int vx = (xq >> 2) * 8 + (s & 7);   // 0..15
        const int vy = s >> 3;                    // 0..3
        const bf16* Ab = Wt + (size_t)2 * DIM * DIM + (size_t)vy * 256 * DIM;
        const bf16* Bb = xb + (size_t)bz * SEQ * DIM + (size_t)vx * 128 * DIM;
        bf16* Cb = Vt + (size_t)bz * DIM * LDP + (size_t)vy * 256 * LDP
                      + (size_t)vx * 128;
        gemm_p3s_core(Ab, Bb, DIM, DIM, DIM, As, Bs, acc);
        write_c128s(Cb, LDP, acc);
    }
    grid.sync();

    // ================= phase 3: scores (p3w + row-sum partials) ========
    {
        f32x4 acc[8][4] = {};
        const int bz = xq & 3;
        const int by = (xq >> 2) * 4 + (s >> 3);  // 0..7
        const int bxg = s & 7;                    // 0..7
        const bf16* Ab = Q  + (size_t)bz * SEQ * DIM + (size_t)by * 256 * DIM;
        const bf16* Bb = Kb + (size_t)bz * SEQ * DIM + (size_t)bxg * 256 * DIM;
        gemm_p3w_core(Ab, Bb, DIM, DIM, DIM, As, Bs, acc);

        bf16* Cb = P + (size_t)bz * SEQ * LDP;
        const int lane = tid & 63;
        const int wave = tid >> 6;
        const int wr = wave >> 2, wc = wave & 3;
        const int r16 = lane & 15, g = lane >> 4;
        const int rowL0 = wr * 128 + g * 4;
        const int colB  = bxg * 256 + wc * 64 + r16;
#pragma unroll
        for (int m = 0; m < 8; ++m)
#pragma unroll
            for (int rr = 0; rr < 4; ++rr) {
                float sum = 0.0f;
#pragma unroll
                for (int n = 0; n < 4; ++n) {
                    const float e = __expf(acc[m][n][rr] * 0.03125f);
                    sum += e;
                    Cb[(size_t)(by * 256 + rowL0 + m * 16 + rr) * LDP
                       + colB + n * 16] = to_bf16(e);
                }
                sum += __shfl_xor(sum, 1);
                sum += __shfl_xor(sum, 2);
                sum += __shfl_xor(sum, 4);
                sum += __shfl_xor(sum, 8);
                if (r16 == 0)
                    rbuf[rowL0 + m * 16 + rr][wc] = sum;
            }
        BARRIER();
        if (tid < 256) {
            const float tot = rbuf[tid][0] + rbuf[tid][1]
                            + rbuf[tid][2] + rbuf[tid][3];
            lsumP[((size_t)bz * 8 + bxg) * SEQ + by * 256 + tid] = tot;
        }
    }
    grid.sync();

    // ================= phase 4: pv (p3s + reduce + divide) =============
    {
        f32x4 acc[4][4] = {};
        const int bz = xq & 3;
        const int by = (xq >> 2) * 4 + (s >> 3);  // 0..7
        const int bx = s & 7;                     // 0..7
        const bf16* Ab = P  + (size_t)bz * SEQ * LDP + (size_t)by * 256 * LDP;
        const bf16* Bb = Vt + (size_t)bz * DIM * LDP + (size_t)bx * 128 * LDP;
        gemm_p3s_core(Ab, Bb, SEQ, LDP, LDP, As, Bs, acc);

        if (tid < 256) {
            const size_t base = (size_t)bz * 8 * SEQ + by * 256 + tid;
            float t = 0.0f;
#pragma unroll
            for (int jj = 0; jj < 8; ++jj)
                t += lsumP[base + (size_t)jj * SEQ];
            sbuf[tid] = t;
        }
        BARRIER();

        float* Cb = out + (size_t)bz * SEQ * DIM;
        const int lane = tid & 63;
        const int wave = tid >> 6;
        const int wr = wave >> 1, wc = wave & 1;
        const int r16 = lane & 15, g = lane >> 4;
        const int rowL0 = wr * 64 + g * 4;
        const int col0  = bx * 128 + wc * 64 + r16;
#pragma unroll
        for (int m = 0; m < 4; ++m)
#pragma unroll
            for (int rr = 0; rr < 4; ++rr) {
                const int rl = rowL0 + m * 16 + rr;
                const float inv = __builtin_amdgcn_rcpf(sbuf[rl]);
                const int row = by * 256 + rl;
#pragma unroll
                for (int n = 0; n < 4; ++n)
                    Cb[(size_t)row * DIM + col0 + n * 16] =
                        acc[m][n][rr] * inv;
            }
    }
}

// ---------------------------------------------------------------------------
extern "C" void kernel_launch(void* const* d_in, const int* in_sizes, int n_in,
                              void* d_out, int out_size, void* d_ws, size_t ws_size,
                              hipStream_t stream)
{
    const float* x  = (const float*)d_in[0];
    const float* wq = (const float*)d_in[1];
    const float* wk = (const float*)d_in[2];
    const float* wv = (const float*)d_in[3];
    float* out = (float*)d_out;
    char* ws = (char*)d_ws;

    // workspace layout (bytes)
    bf16*  xb    = (bf16*)(ws);                   // 16 MB [8192,1024]
    bf16*  Wt    = (bf16*)(ws + (16u << 20));     //  6 MB [3072,1024]
    bf16*  Q     = (bf16*)(ws + (22u << 20));     // 16 MB [8192,1024]
    bf16*  Kb    = (bf16*)(ws + (38u << 20));     // 16 MB [8192,1024]
    bf16*  Vt    = (bf16*)(ws + (54u << 20));     // 17 MB [4][1024][LDP]
    bf16*  P     = (bf16*)(ws + (72u << 20));     // 33 MB [4][2048][LDP]
    float* lsumP = (float*)(ws + (108u << 20));   // 256 KB [4][8][2048]

    void* args[] = { (void*)&x, (void*)&wq, (void*)&wk, (void*)&wv,
                     (void*)&xb, (void*)&Wt, (void*)&Q, (void*)&Kb,
                     (void*)&Vt, (void*)&P, (void*)&lsumP, (void*)&out };
    hipLaunchCooperativeKernel((const void*)fused_attn,
                               dim3(256), dim3(512), args, 0, stream);
}

// Round 14
// 220.744 us; speedup vs baseline: 1.6361x; 1.6361x over previous
//
#include <hip/hip_runtime.h>
#include <cstdint>
#include <cstddef>

typedef __bf16 bf16;
typedef __bf16 bf16x4 __attribute__((ext_vector_type(4)));
typedef __bf16 bf16x8 __attribute__((ext_vector_type(8)));
typedef float  f32x4  __attribute__((ext_vector_type(4)));

#define BATCH 4
#define SEQ   2048
#define DIM   1024
#define LDP   2112   // padded leading dim for P and Vt

// RNE float -> bf16
__device__ __forceinline__ bf16 to_bf16(float f) {
    unsigned u = __builtin_bit_cast(unsigned, f);
    u += 0x7fffu + ((u >> 16) & 1u);
    unsigned short h = (unsigned short)(u >> 16);
    return __builtin_bit_cast(bf16, h);
}

// async global->LDS, 16B per lane. LDS base must be wave-uniform; HW adds lane*16.
__device__ __forceinline__ void load16_lds(const bf16* g, bf16* l) {
    __builtin_amdgcn_global_load_lds(
        (__attribute__((address_space(1))) void*)(g),
        (__attribute__((address_space(3))) void*)(l),
        16, 0, 0);
}

#define BARRIER() __builtin_amdgcn_s_barrier()
#define LGKM0()   asm volatile("s_waitcnt lgkmcnt(0)")
#define VM0()     asm volatile("s_waitcnt vmcnt(0)")
#define VM3()     asm volatile("s_waitcnt vmcnt(3)")
#define VM4()     asm volatile("s_waitcnt vmcnt(4)")

// ---------------------------------------------------------------------------
// r14: revert r13's cooperative fusion (grid.sync measured ~25-30 us EACH on
// 8 XCDs: fused body 276 us vs ~130-175 us of summed r12 kernels). Keep
// r12's proven kernels; single change: MERGE the two independent projection
// dispatches (proj_qk 256 blocks + proj_v 256 blocks) into one 512-block
// dispatch with a block-uniform branch -- removes one of the 4 inter-launch
// boundaries (~12-20 us each per the r12 wall-vs-sum gap). Bodies unchanged.
// Cores: p3w (256x256, BK=32) / p3s (256x128, BK=32), 3-slot counted-vmcnt
// pipeline, stage T+2 during T, never drain vmcnt in steady state; swizzle
// p = c ^ ((row>>1)&3) on global source + ds_read addr (0 conflicts).
// ---------------------------------------------------------------------------

// stage 128 rows x 32 k (8 KB): 1 gload_lds / thread (512 threads).
__device__ __forceinline__ void stage_r32(
    const bf16* __restrict__ srcRow0, int ld, int k0, bf16* dstBase)
{
    const int t = threadIdx.x;                  // 0..511
    const int r = t >> 2;                       // row 0..127
    const int c = (t & 3) ^ ((r >> 1) & 3);     // pre-swizzled global chunk
    load16_lds(srcRow0 + (size_t)r * ld + k0 + c * 8,
               dstBase + (t >> 6) * 512);       // wave-uniform LDS base
}

// ---- p3w: 256x256, BK=32, 8 waves 2Mx4N, per-wave 128x64, acc[8][4] ----
__device__ __forceinline__ void gemm_p3w_core(
    const bf16* __restrict__ Ablk, const bf16* __restrict__ Bblk,
    int K, int lda, int ldb, bf16* As, bf16* Bs, f32x4 acc[8][4])
{
    const int tid  = threadIdx.x;
    const int lane = tid & 63;
    const int wave = tid >> 6;
    const int wr   = wave >> 2;
    const int wc   = wave & 3;
    const int r16  = lane & 15;
    const int g    = lane >> 4;
    const int NT   = K >> 5;
    const int arow0 = wr * 128 + r16;
    const int brow0 = wc * 64 + r16;

    stage_r32(Ablk, lda, 0, As);
    stage_r32(Ablk + (size_t)128 * lda, lda, 0, As + 4096);
    stage_r32(Bblk, ldb, 0, Bs);
    stage_r32(Bblk + (size_t)128 * ldb, ldb, 0, Bs + 4096);
    stage_r32(Ablk, lda, 32, As + 8192);
    stage_r32(Ablk + (size_t)128 * lda, lda, 32, As + 8192 + 4096);
    stage_r32(Bblk, ldb, 32, Bs + 8192);
    stage_r32(Bblk + (size_t)128 * ldb, ldb, 32, Bs + 8192 + 4096);
    VM4();
    BARRIER();

    int c0 = 0, c2 = 2;
    for (int t = 0; t < NT; ++t) {
        bf16* Ac = As + c0 * 8192;
        bf16* Bc = Bs + c0 * 8192;

        bf16x8 a[8], b[4];
#pragma unroll
        for (int n = 0; n < 4; ++n) {
            const int R = brow0 + n * 16;
            b[n] = *(const bf16x8*)(Bc + R * 32 + ((g ^ ((R >> 1) & 3)) * 8));
        }
#pragma unroll
        for (int m = 0; m < 8; ++m) {
            const int R = arow0 + m * 16;
            a[m] = *(const bf16x8*)(Ac + R * 32 + ((g ^ ((R >> 1) & 3)) * 8));
        }
        if (t + 2 < NT) {
            const int k2 = (t + 2) << 5;
            bf16* An = As + c2 * 8192;
            bf16* Bn = Bs + c2 * 8192;
            stage_r32(Ablk, lda, k2, An);
            stage_r32(Ablk + (size_t)128 * lda, lda, k2, An + 4096);
            stage_r32(Bblk, ldb, k2, Bn);
            stage_r32(Bblk + (size_t)128 * ldb, ldb, k2, Bn + 4096);
        }
        __builtin_amdgcn_s_setprio(1);
#pragma unroll
        for (int m = 0; m < 8; ++m)
#pragma unroll
            for (int n = 0; n < 4; ++n)
                acc[m][n] = __builtin_amdgcn_mfma_f32_16x16x32_bf16(
                    a[m], b[n], acc[m][n], 0, 0, 0);
        __builtin_amdgcn_s_setprio(0);

        LGKM0();
        if (t + 1 < NT) {
            if (t + 2 < NT) { VM4(); } else { VM0(); }
        }
        BARRIER();
        c0 = (c0 == 2) ? 0 : c0 + 1;
        c2 = (c2 == 2) ? 0 : c2 + 1;
    }
}

// ---- p3s: 256x128, BK=32, 8 waves 4Mx2N, per-wave 64x64, acc[4][4] -----
__device__ __forceinline__ void gemm_p3s_core(
    const bf16* __restrict__ Ablk, const bf16* __restrict__ Bblk,
    int K, int lda, int ldb, bf16* As, bf16* Bs, f32x4 acc[4][4])
{
    const int tid  = threadIdx.x;
    const int lane = tid & 63;
    const int wave = tid >> 6;
    const int wr   = wave >> 1;
    const int wc   = wave & 1;
    const int r16  = lane & 15;
    const int g    = lane >> 4;
    const int NT   = K >> 5;
    const int arow0 = wr * 64 + r16;
    const int brow0 = wc * 64 + r16;

    stage_r32(Ablk, lda, 0, As);
    stage_r32(Ablk + (size_t)128 * lda, lda, 0, As + 4096);
    stage_r32(Bblk, ldb, 0, Bs);
    stage_r32(Ablk, lda, 32, As + 8192);
    stage_r32(Ablk + (size_t)128 * lda, lda, 32, As + 8192 + 4096);
    stage_r32(Bblk, ldb, 32, Bs + 4096);
    VM3();
    BARRIER();

    int c0 = 0, c2 = 2;
    for (int t = 0; t < NT; ++t) {
        bf16* Ac = As + c0 * 8192;
        bf16* Bc = Bs + c0 * 4096;

        bf16x8 a[4], b[4];
#pragma unroll
        for (int n = 0; n < 4; ++n) {
            const int R = brow0 + n * 16;
            b[n] = *(const bf16x8*)(Bc + R * 32 + ((g ^ ((R >> 1) & 3)) * 8));
        }
#pragma unroll
        for (int m = 0; m < 4; ++m) {
            const int R = arow0 + m * 16;
            a[m] = *(const bf16x8*)(Ac + R * 32 + ((g ^ ((R >> 1) & 3)) * 8));
        }
        if (t + 2 < NT) {
            const int k2 = (t + 2) << 5;
            bf16* An = As + c2 * 8192;
            bf16* Bn = Bs + c2 * 4096;
            stage_r32(Ablk, lda, k2, An);
            stage_r32(Ablk + (size_t)128 * lda, lda, k2, An + 4096);
            stage_r32(Bblk, ldb, k2, Bn);
        }
        __builtin_amdgcn_s_setprio(1);
#pragma unroll
        for (int m = 0; m < 4; ++m)
#pragma unroll
            for (int n = 0; n < 4; ++n)
                acc[m][n] = __builtin_amdgcn_mfma_f32_16x16x32_bf16(
                    a[m], b[n], acc[m][n], 0, 0, 0);
        __builtin_amdgcn_s_setprio(0);

        LGKM0();
        if (t + 1 < NT) {
            if (t + 2 < NT) { VM3(); } else { VM0(); }
        }
        BARRIER();
        c0 = (c0 == 2) ? 0 : c0 + 1;
        c2 = (c2 == 2) ? 0 : c2 + 1;
    }
}

// bf16 C-writer (256x256 core, per-wave 128x64)
__device__ __forceinline__ void write_c256w(
    bf16* __restrict__ Cb, int ldc, const f32x4 acc[8][4])
{
    const int lane = threadIdx.x & 63;
    const int wave = threadIdx.x >> 6;
    const int wr = wave >> 2, wc = wave & 3;
    const int r16 = lane & 15, g = lane >> 4;
    const int row0 = wr * 128 + g * 4;
    const int col0 = wc * 64 + r16;
#pragma unroll
    for (int m = 0; m < 8; ++m)
#pragma unroll
        for (int n = 0; n < 4; ++n)
#pragma unroll
            for (int rr = 0; rr < 4; ++rr)
                Cb[(size_t)(row0 + m * 16 + rr) * ldc + col0 + n * 16] =
                    to_bf16(acc[m][n][rr]);
}

// bf16 C-writer (256x128 core, per-wave 64x64)
__device__ __forceinline__ void write_c128s(
    bf16* __restrict__ Cb, int ldc, const f32x4 acc[4][4])
{
    const int lane = threadIdx.x & 63;
    const int wave = threadIdx.x >> 6;
    const int wr = wave >> 1, wc = wave & 1;
    const int r16 = lane & 15, g = lane >> 4;
    const int row0 = wr * 64 + g * 4;
    const int col0 = wc * 64 + r16;
#pragma unroll
    for (int m = 0; m < 4; ++m)
#pragma unroll
        for (int n = 0; n < 4; ++n)
#pragma unroll
            for (int rr = 0; rr < 4; ++rr)
                Cb[(size_t)(row0 + m * 16 + rr) * ldc + col0 + n * 16] =
                    to_bf16(acc[m][n][rr]);
}

// ---------------------------------------------------------------------------
// MERGED projections: 512 blocks. [0,256): proj_qk (p3w). [256,512): proj_v
// (p3s). Branch is block-uniform; both halves keep r12's exact decode and
// XCD-rect mapping (256 % 8 == 0 preserves block->XCD parity).
// ---------------------------------------------------------------------------
__global__ __launch_bounds__(512, 2) void proj_qkv(
    const bf16* __restrict__ xb, const bf16* __restrict__ Wt,
    bf16* __restrict__ Q, bf16* __restrict__ Kb, bf16* __restrict__ Vt)
{
    __shared__ bf16 As[24576];   // 48 KB
    __shared__ bf16 Bs[24576];   // 48 KB (p3s uses first 24 KB)

    const int p = blockIdx.x;
    if (p < 256) {                        // ---- proj_qk (p3w) ----
        f32x4 acc[8][4] = {};
        const int x = p & 7, s = p >> 3;
        const int my = x * 4 + (s >> 3);          // 0..31
        const int j  = s & 7;                     // 0..7
        const bf16* Ab = xb + (size_t)my * 256 * DIM;
        const bf16* Bb = Wt + (size_t)((j >> 2) ? DIM * DIM : 0)
                            + (size_t)(j & 3) * 256 * DIM;
        bf16* dst = (j >> 2) ? Kb : Q;
        bf16* Cb = dst + (size_t)my * 256 * DIM + (size_t)(j & 3) * 256;
        gemm_p3w_core(Ab, Bb, DIM, DIM, DIM, As, Bs, acc);
        write_c256w(Cb, DIM, acc);
    } else {                              // ---- proj_v (p3s) ----
        f32x4 acc[4][4] = {};
        const int u = p - 256;
        const int x = u & 7, s = u >> 3;
        const int bz = x & 3;
        const int vx = (x >> 2) * 8 + (s & 7);    // 0..15
        const int vy = s >> 3;                    // 0..3
        const bf16* Ab = Wt + (size_t)2 * DIM * DIM + (size_t)vy * 256 * DIM;
        const bf16* Bb = xb + (size_t)bz * SEQ * DIM + (size_t)vx * 128 * DIM;
        bf16* Cb = Vt + (size_t)bz * DIM * LDP + (size_t)vy * 256 * LDP
                      + (size_t)vx * 128;
        gemm_p3s_core(Ab, Bb, DIM, DIM, DIM, As, Bs, acc);
        write_c128s(Cb, LDP, acc);
    }
}

// ---------------------------------------------------------------------------
// scores (p3w): 256 blocks. P' = exp((Q @ K^T)/32) (bf16, ldc=LDP);
// per-block row-sum partials -> lsumP[bz][bxg][row] (non-atomic, no init).
// ---------------------------------------------------------------------------
__global__ __launch_bounds__(512, 2) void gemm_scores_w(
    const bf16* __restrict__ Qm, const bf16* __restrict__ Kb,
    bf16* __restrict__ P, float* __restrict__ lsumP)
{
    __shared__ bf16 As[24576];
    __shared__ bf16 Bs[24576];
    __shared__ float rbuf[256][4];
    f32x4 acc[8][4] = {};

    const int p = blockIdx.x;
    const int x = p & 7, s = p >> 3;
    const int bz = x & 3;
    const int by = (x >> 2) * 4 + (s >> 3);   // 0..7
    const int bxg = s & 7;                    // 0..7
    const bf16* Ab = Qm + (size_t)bz * SEQ * DIM + (size_t)by * 256 * DIM;
    const bf16* Bb = Kb + (size_t)bz * SEQ * DIM + (size_t)bxg * 256 * DIM;
    gemm_p3w_core(Ab, Bb, DIM, DIM, DIM, As, Bs, acc);

    bf16* Cb = P + (size_t)bz * SEQ * LDP;
    const int lane = threadIdx.x & 63;
    const int wave = threadIdx.x >> 6;
    const int wr = wave >> 2, wc = wave & 3;
    const int r16 = lane & 15, g = lane >> 4;
    const int rowL0 = wr * 128 + g * 4;
    const int colB  = bxg * 256 + wc * 64 + r16;
#pragma unroll
    for (int m = 0; m < 8; ++m)
#pragma unroll
        for (int rr = 0; rr < 4; ++rr) {
            float sum = 0.0f;
#pragma unroll
            for (int n = 0; n < 4; ++n) {
                const float e = __expf(acc[m][n][rr] * 0.03125f);
                sum += e;
                Cb[(size_t)(by * 256 + rowL0 + m * 16 + rr) * LDP
                   + colB + n * 16] = to_bf16(e);
            }
            sum += __shfl_xor(sum, 1);
            sum += __shfl_xor(sum, 2);
            sum += __shfl_xor(sum, 4);
            sum += __shfl_xor(sum, 8);
            if (r16 == 0)
                rbuf[rowL0 + m * 16 + rr][wc] = sum;
        }
    BARRIER();
    if (threadIdx.x < 256) {
        const int r = threadIdx.x;
        const float tot = rbuf[r][0] + rbuf[r][1] + rbuf[r][2] + rbuf[r][3];
        lsumP[((size_t)bz * 8 + bxg) * SEQ + by * 256 + r] = tot;
    }
}

// ---------------------------------------------------------------------------
// PV (p3s): 256 blocks. out = (P' @ Vt^T) / l, fp32, 256x128 tiles, NT=64.
// Row sums = sum of 8 lsumP partials via LDS.
// ---------------------------------------------------------------------------
__global__ __launch_bounds__(512, 2) void gemm_pv_s(
    const bf16* __restrict__ P, const bf16* __restrict__ Vt,
    float* __restrict__ C, const float* __restrict__ lsumP)
{
    __shared__ bf16 As[24576];
    __shared__ bf16 Bs[12288];
    __shared__ float sbuf[256];
    f32x4 acc[4][4] = {};

    const int p = blockIdx.x;
    const int x = p & 7, s = p >> 3;
    const int bz = x & 3;
    const int by = (x >> 2) * 4 + (s >> 3);   // 0..7
    const int bx = s & 7;                     // 0..7
    const bf16* Ab = P  + (size_t)bz * SEQ * LDP + (size_t)by * 256 * LDP;
    const bf16* Bb = Vt + (size_t)bz * DIM * LDP + (size_t)bx * 128 * LDP;
    gemm_p3s_core(Ab, Bb, SEQ, LDP, LDP, As, Bs, acc);

    if (threadIdx.x < 256) {
        const int r = threadIdx.x;
        const size_t base = (size_t)bz * 8 * SEQ + by * 256 + r;
        float t = 0.0f;
#pragma unroll
        for (int jj = 0; jj < 8; ++jj)
            t += lsumP[base + (size_t)jj * SEQ];
        sbuf[r] = t;
    }
    BARRIER();

    float* Cb = C + (size_t)bz * SEQ * DIM;
    const int lane = threadIdx.x & 63;
    const int wave = threadIdx.x >> 6;
    const int wr = wave >> 1, wc = wave & 1;
    const int r16 = lane & 15, g = lane >> 4;
    const int rowL0 = wr * 64 + g * 4;
    const int col0  = bx * 128 + wc * 64 + r16;
#pragma unroll
    for (int m = 0; m < 4; ++m)
#pragma unroll
        for (int rr = 0; rr < 4; ++rr) {
            const int rl = rowL0 + m * 16 + rr;
            const float inv = __builtin_amdgcn_rcpf(sbuf[rl]);
            const int row = by * 256 + rl;
#pragma unroll
            for (int n = 0; n < 4; ++n)
                Cb[(size_t)row * DIM + col0 + n * 16] = acc[m][n][rr] * inv;
        }
}

// ---------------------------------------------------------------------------
// Fused prep: blocks [0,8192) cast x fp32->bf16; blocks [8192,11264)
// transpose + cast weights. All branches block-uniform.
// ---------------------------------------------------------------------------
__global__ __launch_bounds__(256) void prep(
    const float* __restrict__ x,  const float* __restrict__ wq,
    const float* __restrict__ wk, const float* __restrict__ wv,
    bf16* __restrict__ xb, bf16* __restrict__ Wt)
{
    __shared__ float tile[32][33];
    const int b = blockIdx.x;
    const int tid = threadIdx.x;
    if (b < 8192) {
        const size_t i = ((size_t)b * 256 + tid) * 4;
        const float4 v = *(const float4*)(x + i);
        bf16x4 o = { to_bf16(v.x), to_bf16(v.y), to_bf16(v.z), to_bf16(v.w) };
        *(bf16x4*)(xb + i) = o;
    } else {
        const int t   = b - 8192;
        const int sel = t >> 10;
        const int n0  = (t & 31) * 32;
        const int k0  = ((t >> 5) & 31) * 32;
        const float* w = (sel == 0) ? wq : (sel == 1) ? wk : wv;
        const int tx = tid & 31, ty = tid >> 5;
#pragma unroll
        for (int j = 0; j < 32; j += 8)
            tile[ty + j][tx] = w[(size_t)(k0 + ty + j) * 1024 + n0 + tx];
        __syncthreads();
        bf16* dst = Wt + (size_t)sel * 1024 * 1024;
#pragma unroll
        for (int j = 0; j < 32; j += 8)
            dst[(size_t)(n0 + ty + j) * 1024 + k0 + tx] = to_bf16(tile[tx][ty + j]);
    }
}

// ---------------------------------------------------------------------------
extern "C" void kernel_launch(void* const* d_in, const int* in_sizes, int n_in,
                              void* d_out, int out_size, void* d_ws, size_t ws_size,
                              hipStream_t stream)
{
    const float* x  = (const float*)d_in[0];
    const float* wq = (const float*)d_in[1];
    const float* wk = (const float*)d_in[2];
    const float* wv = (const float*)d_in[3];
    float* out = (float*)d_out;
    char* ws = (char*)d_ws;

    // workspace layout (bytes)
    bf16*  xb    = (bf16*)(ws);                   // 16 MB [8192,1024]
    bf16*  Wt    = (bf16*)(ws + (16u << 20));     //  6 MB [3072,1024]
    bf16*  Q     = (bf16*)(ws + (22u << 20));     // 16 MB [8192,1024]
    bf16*  Kb    = (bf16*)(ws + (38u << 20));     // 16 MB [8192,1024]
    bf16*  Vt    = (bf16*)(ws + (54u << 20));     // 17 MB [4][1024][LDP]
    bf16*  P     = (bf16*)(ws + (72u << 20));     // 33 MB [4][2048][LDP]
    float* lsumP = (float*)(ws + (108u << 20));   // 256 KB [4][8][2048]

    prep<<<dim3(8192 + 3072), dim3(256), 0, stream>>>(
        x, wq, wk, wv, xb, Wt);

    // merged Q/K/V projections: one dispatch, 512 blocks (2 full CU rounds)
    proj_qkv<<<dim3(512), dim3(512), 0, stream>>>(xb, Wt, Q, Kb, Vt);

    gemm_scores_w<<<dim3(256), dim3(512), 0, stream>>>(Q, Kb, P, lsumP);

    gemm_pv_s<<<dim3(256), dim3(512), 0, stream>>>(P, Vt, out, lsumP);
}